// Round 1
// baseline (436.562 us; speedup 1.0000x reference)
//
#include <hip/hip_runtime.h>

#define ALPHA_F 1000.0f

// ================= GEMM NN + bias: C[M,N] = A[M,K]*B[K,N] + bias, fp32 =====
// 64x64 tile, BK=16, 256 threads, 4x4 micro-tile.
__global__ __launch_bounds__(256) void gemm_nn_bias(
    const float* __restrict__ A, const float* __restrict__ Bm,
    const float* __restrict__ bias, float* __restrict__ C,
    int M, int N, int K)
{
    __shared__ float As[16 * 68];   // [kk][row], transposed store, pad 68
    __shared__ float Bs[16 * 68];   // [kk][col]
    const int t  = threadIdx.x;
    const int tx = t & 15, ty = t >> 4;
    const int n0 = blockIdx.x * 64, m0 = blockIdx.y * 64;
    const int arow = t >> 2, aq = t & 3;    // A tile: 64 rows x 16 k (float4 per thread)
    const int brow = t >> 4, bq = t & 15;   // B tile: 16 rows x 64 n

    float acc[4][4] = {};

    for (int k0 = 0; k0 < K; k0 += 16) {
        const float4 av = *(const float4*)(A + (size_t)(m0 + arow) * K + k0 + aq * 4);
        const float4 bv = *(const float4*)(Bm + (size_t)(k0 + brow) * N + n0 + bq * 4);
        __syncthreads();
        As[(aq * 4 + 0) * 68 + arow] = av.x;
        As[(aq * 4 + 1) * 68 + arow] = av.y;
        As[(aq * 4 + 2) * 68 + arow] = av.z;
        As[(aq * 4 + 3) * 68 + arow] = av.w;
        *(float4*)(Bs + brow * 68 + bq * 4) = bv;
        __syncthreads();
        #pragma unroll
        for (int kk = 0; kk < 16; ++kk) {
            const float4 a4 = *(const float4*)(As + kk * 68 + ty * 4);
            const float4 b4 = *(const float4*)(Bs + kk * 68 + tx * 4);
            acc[0][0] += a4.x * b4.x; acc[0][1] += a4.x * b4.y;
            acc[0][2] += a4.x * b4.z; acc[0][3] += a4.x * b4.w;
            acc[1][0] += a4.y * b4.x; acc[1][1] += a4.y * b4.y;
            acc[1][2] += a4.y * b4.z; acc[1][3] += a4.y * b4.w;
            acc[2][0] += a4.z * b4.x; acc[2][1] += a4.z * b4.y;
            acc[2][2] += a4.z * b4.z; acc[2][3] += a4.z * b4.w;
            acc[3][0] += a4.w * b4.x; acc[3][1] += a4.w * b4.y;
            acc[3][2] += a4.w * b4.z; acc[3][3] += a4.w * b4.w;
        }
    }

    const float4 bias4 = *(const float4*)(bias + n0 + tx * 4);
    #pragma unroll
    for (int i = 0; i < 4; ++i) {
        float4 c4;
        c4.x = acc[i][0] + bias4.x;
        c4.y = acc[i][1] + bias4.y;
        c4.z = acc[i][2] + bias4.z;
        c4.w = acc[i][3] + bias4.w;
        *(float4*)(C + (size_t)(m0 + ty * 4 + i) * N + n0 + tx * 4) = c4;
    }
}

// ================= row sum-of-squares: dst[r] = sum_j src[r][j]^2, ncols=256
__global__ __launch_bounds__(256) void row_sumsq(
    const float* __restrict__ src, float* __restrict__ dst)
{
    const int wid = threadIdx.x >> 6, lane = threadIdx.x & 63;
    const int row = blockIdx.x * 4 + wid;
    const float4 v = *(const float4*)(src + (size_t)row * 256 + lane * 4);
    float s = v.x * v.x + v.y * v.y + v.z * v.z + v.w * v.w;
    #pragma unroll
    for (int off = 32; off >= 1; off >>= 1) s += __shfl_xor(s, off, 64);
    if (lane == 0) dst[row] = s;
}

// ================= fused dist + softmin ====================================
// Per block: 32 rows (b) x all 256 clusters (k).
// S = emb @ creps^T in registers; dist = enorm - 2S + cnorm; softmin over k;
// writes weighted_dist[k][b] (row-major [256][8192]).
__global__ __launch_bounds__(256) void dist_softmin(
    const float* __restrict__ emb, const float* __restrict__ creps,
    const float* __restrict__ enorm, const float* __restrict__ cnorm,
    float* __restrict__ out)
{
    __shared__ float sm[13024];
    float* As   = sm;            // [16][36]  emb tile (transposed)
    float* Bs   = sm + 576;      // [16][260] creps tile (transposed)
    float* D    = sm + 4736;     // [32][257] dist tile
    float* MINV = sm + 12960;    // [32]
    float* SUMV = sm + 12992;    // [32]

    const int t  = threadIdx.x;
    const int tx = t & 15, ty = t >> 4;     // ty: row group (2 rows), tx: k group
    const int b0 = blockIdx.x * 32;
    const int arow = t >> 3, aq = t & 7;    // A tile: 32 rows x 16 j (float2/thread)

    float acc[2][16] = {};

    for (int j0 = 0; j0 < 256; j0 += 16) {
        const float2 av = *(const float2*)(emb + (size_t)(b0 + arow) * 256 + j0 + aq * 2);
        const float4 bv0 = *(const float4*)(creps + (size_t)t * 256 + j0 + 0);
        const float4 bv1 = *(const float4*)(creps + (size_t)t * 256 + j0 + 4);
        const float4 bv2 = *(const float4*)(creps + (size_t)t * 256 + j0 + 8);
        const float4 bv3 = *(const float4*)(creps + (size_t)t * 256 + j0 + 12);
        __syncthreads();
        As[(aq * 2 + 0) * 36 + arow] = av.x;
        As[(aq * 2 + 1) * 36 + arow] = av.y;
        Bs[ 0 * 260 + t] = bv0.x; Bs[ 1 * 260 + t] = bv0.y;
        Bs[ 2 * 260 + t] = bv0.z; Bs[ 3 * 260 + t] = bv0.w;
        Bs[ 4 * 260 + t] = bv1.x; Bs[ 5 * 260 + t] = bv1.y;
        Bs[ 6 * 260 + t] = bv1.z; Bs[ 7 * 260 + t] = bv1.w;
        Bs[ 8 * 260 + t] = bv2.x; Bs[ 9 * 260 + t] = bv2.y;
        Bs[10 * 260 + t] = bv2.z; Bs[11 * 260 + t] = bv2.w;
        Bs[12 * 260 + t] = bv3.x; Bs[13 * 260 + t] = bv3.y;
        Bs[14 * 260 + t] = bv3.z; Bs[15 * 260 + t] = bv3.w;
        __syncthreads();
        #pragma unroll
        for (int jj = 0; jj < 16; ++jj) {
            const float a0 = As[jj * 36 + ty * 2 + 0];
            const float a1 = As[jj * 36 + ty * 2 + 1];
            #pragma unroll
            for (int nk = 0; nk < 4; ++nk) {
                const float4 b4 = *(const float4*)(Bs + jj * 260 + nk * 64 + tx * 4);
                acc[0][nk * 4 + 0] += a0 * b4.x; acc[0][nk * 4 + 1] += a0 * b4.y;
                acc[0][nk * 4 + 2] += a0 * b4.z; acc[0][nk * 4 + 3] += a0 * b4.w;
                acc[1][nk * 4 + 0] += a1 * b4.x; acc[1][nk * 4 + 1] += a1 * b4.y;
                acc[1][nk * 4 + 2] += a1 * b4.z; acc[1][nk * 4 + 3] += a1 * b4.w;
            }
        }
    }

    // dist = enorm[b] - 2*S + cnorm[k] -> LDS
    float en[2];
    en[0] = enorm[b0 + ty * 2 + 0];
    en[1] = enorm[b0 + ty * 2 + 1];
    #pragma unroll
    for (int nk = 0; nk < 4; ++nk) {
        #pragma unroll
        for (int q = 0; q < 4; ++q) {
            const int k = nk * 64 + tx * 4 + q;
            const float cn = cnorm[k];
            D[(ty * 2 + 0) * 257 + k] = en[0] - 2.0f * acc[0][nk * 4 + q] + cn;
            D[(ty * 2 + 1) * 257 + k] = en[1] - 2.0f * acc[1][nk * 4 + q] + cn;
        }
    }
    __syncthreads();

    // phase 1: per-row min over 256, then sum of exp
    const int w = t >> 6, lane = t & 63;
    #pragma unroll
    for (int rr = 0; rr < 8; ++rr) {
        const int r = w * 8 + rr;
        const float d0 = D[r * 257 + lane +   0];
        const float d1 = D[r * 257 + lane +  64];
        const float d2 = D[r * 257 + lane + 128];
        const float d3 = D[r * 257 + lane + 192];
        float mn = fminf(fminf(d0, d1), fminf(d2, d3));
        #pragma unroll
        for (int off = 32; off >= 1; off >>= 1) mn = fminf(mn, __shfl_xor(mn, off, 64));
        float s = expf(-ALPHA_F * (d0 - mn)) + expf(-ALPHA_F * (d1 - mn))
                + expf(-ALPHA_F * (d2 - mn)) + expf(-ALPHA_F * (d3 - mn));
        #pragma unroll
        for (int off = 32; off >= 1; off >>= 1) s += __shfl_xor(s, off, 64);
        if (lane == 0) { MINV[r] = mn; SUMV[r] = s; }
    }
    __syncthreads();

    // phase 2: weighted = d * exp(-a*(d-min)) / sum, write out[k][b] coalesced
    const int b = t & 31, kg = t >> 5;
    const float mn = MINV[b], sv = SUMV[b];
    #pragma unroll
    for (int kk = 0; kk < 32; ++kk) {
        const int k = kk * 8 + kg;
        const float dv = D[b * 257 + k];
        out[(size_t)k * 8192 + b0 + b] = dv * expf(-ALPHA_F * (dv - mn)) / sv;
    }
}

// ================= launch ==================================================
extern "C" void kernel_launch(void* const* d_in, const int* in_sizes, int n_in,
                              void* d_out, int out_size, void* d_ws, size_t ws_size,
                              hipStream_t stream) {
    const float* x     = (const float*)d_in[0];   // [8192,2048]
    const float* W_enc = (const float*)d_in[1];   // [2048,256]
    const float* b_enc = (const float*)d_in[2];   // [256]
    const float* W_dec = (const float*)d_in[3];   // [256,2048]
    const float* b_dec = (const float*)d_in[4];   // [2048]
    const float* creps = (const float*)d_in[5];   // [256,256]

    float* out_w   = (float*)d_out;               // [256,8192]
    float* out_rec = out_w + (size_t)256 * 8192;  // [8192,2048]

    float* emb   = (float*)d_ws;                  // 8192*256 fp32 = 8 MB
    float* enorm = emb + (size_t)8192 * 256;      // 8192
    float* cnorm = enorm + 8192;                  // 256

    // emb = x @ W_enc + b_enc   (M=8192, N=256, K=2048)
    gemm_nn_bias<<<dim3(256 / 64, 8192 / 64), 256, 0, stream>>>(
        x, W_enc, b_enc, emb, 8192, 256, 2048);

    // norms
    row_sumsq<<<8192 / 4, 256, 0, stream>>>(emb, enorm);
    row_sumsq<<<256 / 4, 256, 0, stream>>>(creps, cnorm);

    // weighted_dist (output 0)
    dist_softmin<<<8192 / 32, 256, 0, stream>>>(emb, creps, enorm, cnorm, out_w);

    // reconstruction = emb @ W_dec + b_dec  (M=8192, N=2048, K=256) (output 1)
    gemm_nn_bias<<<dim3(2048 / 64, 8192 / 64), 256, 0, stream>>>(
        emb, W_dec, b_dec, out_rec, 8192, 2048, 256);
}

// Round 2
// 248.886 us; speedup vs baseline: 1.7541x; 1.7541x over previous
//
#include <hip/hip_runtime.h>

#define ALPHA_F 1000.0f

typedef _Float16 half8 __attribute__((ext_vector_type(8)));
typedef _Float16 half4 __attribute__((ext_vector_type(4)));
typedef float floatx4 __attribute__((ext_vector_type(4)));

__device__ __forceinline__ void gload_lds16(const void* g, void* l) {
    __builtin_amdgcn_global_load_lds(
        (const __attribute__((address_space(1))) unsigned int*)g,
        (__attribute__((address_space(3))) unsigned int*)l, 16, 0, 0);
}

// ============ pre-split W_enc (scaled x256) into fp16 hi/lo, frag-order =====
// frag-order: idx = ((kc*16 + nt)*64 + lane)*8 + j ; lane=(n&15)|((k8&3)<<4), j=k&7
__global__ __launch_bounds__(256) void split_wenc(
    const float* __restrict__ W, _Float16* __restrict__ Wh, _Float16* __restrict__ Wl)
{
    const int q = blockIdx.x * 256 + threadIdx.x;   // 65536 threads
    const int n = q & 255, k8 = q >> 8;             // k8: 0..255
    const int k = k8 * 8;
    half8 h, l;
    #pragma unroll
    for (int i = 0; i < 8; ++i) {
        const float v = W[(size_t)(k + i) * 256 + n] * 256.0f;
        const _Float16 hi = (_Float16)v;
        h[i] = hi;
        l[i] = (_Float16)(v - (float)hi);
    }
    const int kc = k >> 5, nt = n >> 4;
    const int lane = (n & 15) | ((k8 & 3) << 4);
    const size_t idx = (size_t)((kc * 16 + nt) * 64 + lane) * 8;
    *(half8*)(Wh + idx) = h;
    *(half8*)(Wl + idx) = l;
}

// ============ pre-split W_dec into fp16 hi, frag-order ======================
__global__ __launch_bounds__(256) void split_wdec(
    const float* __restrict__ W, _Float16* __restrict__ Wh)
{
    const int q = blockIdx.x * 256 + threadIdx.x;   // 65536 threads
    const int n = q & 2047, k8 = q >> 11;           // k8: 0..31
    const int k = k8 * 8;
    half8 h;
    #pragma unroll
    for (int i = 0; i < 8; ++i) h[i] = (_Float16)W[(size_t)(k + i) * 2048 + n];
    const int kc = k8 >> 2, nt = n >> 4;
    const int lane = (n & 15) | ((k8 & 3) << 4);
    *(half8*)(Wh + (size_t)((kc * 128 + nt) * 64 + lane) * 8) = h;
}

// ============ emb = x @ W_enc + b_enc via fp16x3 MFMA =======================
// BM=32, BN=128, BK=32, 256 threads (4 waves), per-wave 32x32 (2m x 2n tiles).
// grid (2, 256). Writes emb fp32 row-major + emb_h fp16 frag-order.
__global__ __launch_bounds__(256) void emb_gemm(
    const float* __restrict__ x, const _Float16* __restrict__ Wh,
    const _Float16* __restrict__ Wl, const float* __restrict__ b_enc,
    float* __restrict__ emb, _Float16* __restrict__ emb_h)
{
    __shared__ _Float16 Ah[2 * 64 * 8], Al[2 * 64 * 8];  // 2KB each
    __shared__ _Float16 Bh[8 * 64 * 8], Bl[8 * 64 * 8];  // 8KB each
    const int t = threadIdx.x, lane = t & 63, w = t >> 6;
    const int nb = blockIdx.x, mb = blockIdx.y;
    const int m0 = mb * 32;

    // A staging geometry: thread t loads float4 of row am, cols aq..aq+3
    const int am = t >> 3, aq = (t & 7) * 4;
    const int asub = am >> 4;
    const int alane = (am & 15) | (((aq >> 3) & 3) << 4);
    const int aj = aq & 7;                               // 0 or 4
    _Float16* AhW = Ah + (asub * 64 + alane) * 8 + aj;
    _Float16* AlW = Al + (asub * 64 + alane) * 8 + aj;
    const float* xP = x + (size_t)(m0 + am) * 2048 + aq;

    floatx4 acc[2][2] = {};

    for (int kc = 0; kc < 64; ++kc) {
        const float4 v = *(const float4*)(xP + kc * 32);
        __syncthreads();                                 // prev compute done
        // B: global (frag-order) -> LDS, 16B per lane
        const _Float16* bh_src = Wh + (size_t)(kc * 16 + nb * 8) * 512;
        const _Float16* bl_src = Wl + (size_t)(kc * 16 + nb * 8) * 512;
        #pragma unroll
        for (int i = 0; i < 2; ++i) {
            const int c = w * 2 + i;
            gload_lds16(bh_src + (size_t)c * 512 + lane * 8, Bh + c * 512);
            gload_lds16(bl_src + (size_t)c * 512 + lane * 8, Bl + c * 512);
        }
        // A: split fp32 -> hi/lo fp16 into frag-order LDS
        half4 h4, l4;
        {
            const float vv0 = v.x, vv1 = v.y, vv2 = v.z, vv3 = v.w;
            _Float16 hi;
            hi = (_Float16)vv0; h4[0] = hi; l4[0] = (_Float16)(vv0 - (float)hi);
            hi = (_Float16)vv1; h4[1] = hi; l4[1] = (_Float16)(vv1 - (float)hi);
            hi = (_Float16)vv2; h4[2] = hi; l4[2] = (_Float16)(vv2 - (float)hi);
            hi = (_Float16)vv3; h4[3] = hi; l4[3] = (_Float16)(vv3 - (float)hi);
        }
        *(half4*)AhW = h4;
        *(half4*)AlW = l4;
        __syncthreads();                                 // B arrived, A written

        half8 ah[2], al[2], bhf[2], blf[2];
        #pragma unroll
        for (int s = 0; s < 2; ++s) {
            ah[s] = *(const half8*)(Ah + (s * 64 + lane) * 8);
            al[s] = *(const half8*)(Al + (s * 64 + lane) * 8);
        }
        #pragma unroll
        for (int u = 0; u < 2; ++u) {
            bhf[u] = *(const half8*)(Bh + ((2 * w + u) * 64 + lane) * 8);
            blf[u] = *(const half8*)(Bl + ((2 * w + u) * 64 + lane) * 8);
        }
        #pragma unroll
        for (int mi = 0; mi < 2; ++mi) {
            #pragma unroll
            for (int ni = 0; ni < 2; ++ni) {
                acc[mi][ni] = __builtin_amdgcn_mfma_f32_16x16x32_f16(ah[mi], blf[ni], acc[mi][ni], 0, 0, 0);
                acc[mi][ni] = __builtin_amdgcn_mfma_f32_16x16x32_f16(al[mi], bhf[ni], acc[mi][ni], 0, 0, 0);
                acc[mi][ni] = __builtin_amdgcn_mfma_f32_16x16x32_f16(ah[mi], bhf[ni], acc[mi][ni], 0, 0, 0);
            }
        }
    }

    // epilogue: emb = acc/256 + bias ; also emb_h (fp16, frag-order)
    const float inv = 1.0f / 256.0f;
    #pragma unroll
    for (int mi = 0; mi < 2; ++mi) {
        #pragma unroll
        for (int ni = 0; ni < 2; ++ni) {
            const int col = nb * 128 + (2 * w + ni) * 16 + (lane & 15);
            const float bias = b_enc[col];
            const int rowBase = m0 + mi * 16 + (lane >> 4) * 4;
            const int kc2 = col >> 5;
            const int cbits = ((col >> 3) & 3) << 4;
            const int jj = col & 7;
            #pragma unroll
            for (int r = 0; r < 4; ++r) {
                const float val = acc[mi][ni][r] * inv + bias;
                emb[(size_t)(rowBase + r) * 256 + col] = val;
                const int lane2 = (((lane >> 4) * 4 + r) | cbits);
                emb_h[(size_t)(((mb * 2 + mi) * 8 + kc2) * 64 + lane2) * 8 + jj] = (_Float16)val;
            }
        }
    }
}

// ============ recon = emb @ W_dec + b_dec via fp16 MFMA =====================
// 128x128 tile, BK=32 (8 chunks), 256 threads, per-wave 64x64 (4x4 tiles).
// grid (16, 64). A (emb_h) and B (Wdh) both frag-order -> pure global_load_lds.
__global__ __launch_bounds__(256) void recon_gemm(
    const _Float16* __restrict__ embh, const _Float16* __restrict__ Wdh,
    const float* __restrict__ b_dec, float* __restrict__ out)
{
    __shared__ _Float16 Ah[8 * 64 * 8];   // 8KB
    __shared__ _Float16 Bh[8 * 64 * 8];   // 8KB
    const int t = threadIdx.x, lane = t & 63, w = t >> 6;
    const int wm = w >> 1, wn = w & 1;
    const int nb = blockIdx.x, mb = blockIdx.y;

    floatx4 acc[4][4] = {};

    for (int kc = 0; kc < 8; ++kc) {
        __syncthreads();
        #pragma unroll
        for (int i = 0; i < 2; ++i) {
            const int c = w * 2 + i;
            gload_lds16(embh + (size_t)(((mb * 8 + c) * 8 + kc) * 64 + lane) * 8, Ah + c * 512);
            gload_lds16(Wdh + (size_t)((kc * 128 + nb * 8 + c) * 64 + lane) * 8, Bh + c * 512);
        }
        __syncthreads();
        half8 a[4], b[4];
        #pragma unroll
        for (int mi = 0; mi < 4; ++mi) a[mi] = *(const half8*)(Ah + ((wm * 4 + mi) * 64 + lane) * 8);
        #pragma unroll
        for (int ni = 0; ni < 4; ++ni) b[ni] = *(const half8*)(Bh + ((wn * 4 + ni) * 64 + lane) * 8);
        #pragma unroll
        for (int mi = 0; mi < 4; ++mi)
            #pragma unroll
            for (int ni = 0; ni < 4; ++ni)
                acc[mi][ni] = __builtin_amdgcn_mfma_f32_16x16x32_f16(a[mi], b[ni], acc[mi][ni], 0, 0, 0);
    }

    #pragma unroll
    for (int ni = 0; ni < 4; ++ni) {
        const int col = nb * 128 + (wn * 4 + ni) * 16 + (lane & 15);
        const float bias = b_dec[col];
        #pragma unroll
        for (int mi = 0; mi < 4; ++mi) {
            const int rowBase = mb * 128 + (wm * 4 + mi) * 16 + (lane >> 4) * 4;
            #pragma unroll
            for (int r = 0; r < 4; ++r)
                out[(size_t)(rowBase + r) * 2048 + col] = acc[mi][ni][r] + bias;
        }
    }
}

// ============ row sum-of-squares: dst[r] = sum_j src[r][j]^2, ncols=256 =====
__global__ __launch_bounds__(256) void row_sumsq(
    const float* __restrict__ src, float* __restrict__ dst)
{
    const int wid = threadIdx.x >> 6, lane = threadIdx.x & 63;
    const int row = blockIdx.x * 4 + wid;
    const float4 v = *(const float4*)(src + (size_t)row * 256 + lane * 4);
    float s = v.x * v.x + v.y * v.y + v.z * v.z + v.w * v.w;
    #pragma unroll
    for (int off = 32; off >= 1; off >>= 1) s += __shfl_xor(s, off, 64);
    if (lane == 0) dst[row] = s;
}

// ============ fused dist + softmin (fp32 VALU, unchanged) ===================
__global__ __launch_bounds__(256) void dist_softmin(
    const float* __restrict__ emb, const float* __restrict__ creps,
    const float* __restrict__ enorm, const float* __restrict__ cnorm,
    float* __restrict__ out)
{
    __shared__ float sm[13024];
    float* As   = sm;            // [16][36]
    float* Bs   = sm + 576;      // [16][260]
    float* D    = sm + 4736;     // [32][257]
    float* MINV = sm + 12960;    // [32]
    float* SUMV = sm + 12992;    // [32]

    const int t  = threadIdx.x;
    const int tx = t & 15, ty = t >> 4;
    const int b0 = blockIdx.x * 32;
    const int arow = t >> 3, aq = t & 7;

    float acc[2][16] = {};

    for (int j0 = 0; j0 < 256; j0 += 16) {
        const float2 av = *(const float2*)(emb + (size_t)(b0 + arow) * 256 + j0 + aq * 2);
        const float4 bv0 = *(const float4*)(creps + (size_t)t * 256 + j0 + 0);
        const float4 bv1 = *(const float4*)(creps + (size_t)t * 256 + j0 + 4);
        const float4 bv2 = *(const float4*)(creps + (size_t)t * 256 + j0 + 8);
        const float4 bv3 = *(const float4*)(creps + (size_t)t * 256 + j0 + 12);
        __syncthreads();
        As[(aq * 2 + 0) * 36 + arow] = av.x;
        As[(aq * 2 + 1) * 36 + arow] = av.y;
        Bs[ 0 * 260 + t] = bv0.x; Bs[ 1 * 260 + t] = bv0.y;
        Bs[ 2 * 260 + t] = bv0.z; Bs[ 3 * 260 + t] = bv0.w;
        Bs[ 4 * 260 + t] = bv1.x; Bs[ 5 * 260 + t] = bv1.y;
        Bs[ 6 * 260 + t] = bv1.z; Bs[ 7 * 260 + t] = bv1.w;
        Bs[ 8 * 260 + t] = bv2.x; Bs[ 9 * 260 + t] = bv2.y;
        Bs[10 * 260 + t] = bv2.z; Bs[11 * 260 + t] = bv2.w;
        Bs[12 * 260 + t] = bv3.x; Bs[13 * 260 + t] = bv3.y;
        Bs[14 * 260 + t] = bv3.z; Bs[15 * 260 + t] = bv3.w;
        __syncthreads();
        #pragma unroll
        for (int jj = 0; jj < 16; ++jj) {
            const float a0 = As[jj * 36 + ty * 2 + 0];
            const float a1 = As[jj * 36 + ty * 2 + 1];
            #pragma unroll
            for (int nk = 0; nk < 4; ++nk) {
                const float4 b4 = *(const float4*)(Bs + jj * 260 + nk * 64 + tx * 4);
                acc[0][nk * 4 + 0] += a0 * b4.x; acc[0][nk * 4 + 1] += a0 * b4.y;
                acc[0][nk * 4 + 2] += a0 * b4.z; acc[0][nk * 4 + 3] += a0 * b4.w;
                acc[1][nk * 4 + 0] += a1 * b4.x; acc[1][nk * 4 + 1] += a1 * b4.y;
                acc[1][nk * 4 + 2] += a1 * b4.z; acc[1][nk * 4 + 3] += a1 * b4.w;
            }
        }
    }

    float en[2];
    en[0] = enorm[b0 + ty * 2 + 0];
    en[1] = enorm[b0 + ty * 2 + 1];
    #pragma unroll
    for (int nk = 0; nk < 4; ++nk) {
        #pragma unroll
        for (int q = 0; q < 4; ++q) {
            const int k = nk * 64 + tx * 4 + q;
            const float cn = cnorm[k];
            D[(ty * 2 + 0) * 257 + k] = en[0] - 2.0f * acc[0][nk * 4 + q] + cn;
            D[(ty * 2 + 1) * 257 + k] = en[1] - 2.0f * acc[1][nk * 4 + q] + cn;
        }
    }
    __syncthreads();

    const int w = t >> 6, lane = t & 63;
    #pragma unroll
    for (int rr = 0; rr < 8; ++rr) {
        const int r = w * 8 + rr;
        const float d0 = D[r * 257 + lane +   0];
        const float d1 = D[r * 257 + lane +  64];
        const float d2 = D[r * 257 + lane + 128];
        const float d3 = D[r * 257 + lane + 192];
        float mn = fminf(fminf(d0, d1), fminf(d2, d3));
        #pragma unroll
        for (int off = 32; off >= 1; off >>= 1) mn = fminf(mn, __shfl_xor(mn, off, 64));
        float s = expf(-ALPHA_F * (d0 - mn)) + expf(-ALPHA_F * (d1 - mn))
                + expf(-ALPHA_F * (d2 - mn)) + expf(-ALPHA_F * (d3 - mn));
        #pragma unroll
        for (int off = 32; off >= 1; off >>= 1) s += __shfl_xor(s, off, 64);
        if (lane == 0) { MINV[r] = mn; SUMV[r] = s; }
    }
    __syncthreads();

    const int b = t & 31, kg = t >> 5;
    const float mn = MINV[b], sv = SUMV[b];
    #pragma unroll
    for (int kk = 0; kk < 32; ++kk) {
        const int k = kk * 8 + kg;
        const float dv = D[b * 257 + k];
        out[(size_t)k * 8192 + b0 + b] = dv * expf(-ALPHA_F * (dv - mn)) / sv;
    }
}

// ================= launch ==================================================
extern "C" void kernel_launch(void* const* d_in, const int* in_sizes, int n_in,
                              void* d_out, int out_size, void* d_ws, size_t ws_size,
                              hipStream_t stream) {
    const float* x     = (const float*)d_in[0];   // [8192,2048]
    const float* W_enc = (const float*)d_in[1];   // [2048,256]
    const float* b_enc = (const float*)d_in[2];   // [256]
    const float* W_dec = (const float*)d_in[3];   // [256,2048]
    const float* b_dec = (const float*)d_in[4];   // [2048]
    const float* creps = (const float*)d_in[5];   // [256,256]

    float* out_w   = (float*)d_out;               // [256,8192]
    float* out_rec = out_w + (size_t)256 * 8192;  // [8192,2048]

    float*     emb   = (float*)d_ws;                       // 8 MB
    float*     enorm = emb + (size_t)8192 * 256;           // 32 KB
    float*     cnorm = enorm + 8192;                       // 1 KB
    _Float16*  embh  = (_Float16*)(cnorm + 256);           // 4 MB, frag-order
    _Float16*  Whf   = embh + (size_t)8192 * 256;          // 1 MB
    _Float16*  Wlf   = Whf + (size_t)2048 * 256;           // 1 MB
    _Float16*  Wdh   = Wlf + (size_t)2048 * 256;           // 1 MB

    split_wenc<<<256, 256, 0, stream>>>(W_enc, Whf, Wlf);
    split_wdec<<<256, 256, 0, stream>>>(W_dec, Wdh);

    // emb = x @ W_enc + b_enc (fp16x3 MFMA), also emits emb_h (fp16 frag-order)
    emb_gemm<<<dim3(2, 256), 256, 0, stream>>>(x, Whf, Wlf, b_enc, emb, embh);

    row_sumsq<<<8192 / 4, 256, 0, stream>>>(emb, enorm);
    row_sumsq<<<256 / 4, 256, 0, stream>>>(creps, cnorm);

    // weighted_dist (output 0)
    dist_softmin<<<8192 / 32, 256, 0, stream>>>(emb, creps, enorm, cnorm, out_w);

    // reconstruction (output 1), fp16 MFMA
    recon_gemm<<<dim3(16, 64), 256, 0, stream>>>(embh, Wdh, b_dec, out_rec);
}

// Round 3
// 210.244 us; speedup vs baseline: 2.0765x; 1.1838x over previous
//
#include <hip/hip_runtime.h>

#define ALPHA_F 1000.0f

typedef _Float16 half8 __attribute__((ext_vector_type(8)));
typedef float floatx4 __attribute__((ext_vector_type(4)));

__device__ __forceinline__ void gload_lds16(const void* g, void* l) {
    __builtin_amdgcn_global_load_lds(
        (const __attribute__((address_space(1))) unsigned int*)g,
        (__attribute__((address_space(3))) unsigned int*)l, 16, 0, 0);
}

// ============ pre-split W_enc (scaled x256) into fp16 hi/lo, frag-order =====
// idx = ((kc*16 + nt)*64 + lane)*8 + j ; lane=(n&15)|(((k>>3)&3)<<4), j=k&7
__global__ __launch_bounds__(256) void split_wenc(
    const float* __restrict__ W, _Float16* __restrict__ Wh, _Float16* __restrict__ Wl)
{
    const int q = blockIdx.x * 256 + threadIdx.x;   // 65536 threads
    const int n = q & 255, k8 = q >> 8;             // k8: 0..255
    const int k = k8 * 8;
    half8 h, l;
    #pragma unroll
    for (int i = 0; i < 8; ++i) {
        const float v = W[(size_t)(k + i) * 256 + n] * 256.0f;
        const _Float16 hi = (_Float16)v;
        h[i] = hi;
        l[i] = (_Float16)(v - (float)hi);
    }
    const int kc = k >> 5, nt = n >> 4;
    const int lane = (n & 15) | ((k8 & 3) << 4);
    const size_t idx = (size_t)((kc * 16 + nt) * 64 + lane) * 8;
    *(half8*)(Wh + idx) = h;
    *(half8*)(Wl + idx) = l;
}

// ============ pre-split W_dec into fp16 hi, frag-order ======================
__global__ __launch_bounds__(256) void split_wdec(
    const float* __restrict__ W, _Float16* __restrict__ Wh)
{
    const int q = blockIdx.x * 256 + threadIdx.x;   // 65536 threads
    const int n = q & 2047, k8 = q >> 11;           // k8: 0..31
    const int k = k8 * 8;
    half8 h;
    #pragma unroll
    for (int i = 0; i < 8; ++i) h[i] = (_Float16)W[(size_t)(k + i) * 2048 + n];
    const int kc = k8 >> 2, nt = n >> 4;
    const int lane = (n & 15) | ((k8 & 3) << 4);
    *(half8*)(Wh + (size_t)((kc * 128 + nt) * 64 + lane) * 8) = h;
}

// ============ pre-split creps into fp16 hi + scaled lo (x2048), frag-order ==
__global__ __launch_bounds__(256) void split_creps(
    const float* __restrict__ C, _Float16* __restrict__ Ch, _Float16* __restrict__ Cl)
{
    const int q = blockIdx.x * 256 + threadIdx.x;   // 8192 threads
    const int n = q & 255, j8 = q >> 8;             // j8: 0..31
    const int j = j8 * 8;
    half8 h, l;
    #pragma unroll
    for (int i = 0; i < 8; ++i) {
        const float v = C[(size_t)n * 256 + j + i];
        const _Float16 hi = (_Float16)v;
        h[i] = hi;
        l[i] = (_Float16)((v - (float)hi) * 2048.0f);
    }
    const int jc = j >> 5, nt = n >> 4;
    const int lane = (n & 15) | ((j8 & 3) << 4);
    const size_t idx = (size_t)((jc * 16 + nt) * 64 + lane) * 8;
    *(half8*)(Ch + idx) = h;
    *(half8*)(Cl + idx) = l;
}

// ============ emb partials: P[kk] = x[:,kk*512:+512] @ W_enc[kk...] =========
// BM=64, BN=256 (full N), BK=32, split-K=4. grid (4, 128). 4 waves,
// wave tile 64x64: 48 MFMA : 16 ds_read_b128 per iter.
__global__ __launch_bounds__(256) void emb_gemm(
    const float* __restrict__ x, const _Float16* __restrict__ Wh,
    const _Float16* __restrict__ Wl, float* __restrict__ P)
{
    __shared__ _Float16 Ah[4 * 64 * 8], Al[4 * 64 * 8];   // 4KB each
    __shared__ _Float16 Bh[16 * 64 * 8], Bl[16 * 64 * 8]; // 16KB each
    const int t = threadIdx.x, lane = t & 63, w = t >> 6;
    const int kk = blockIdx.x;        // split-K chunk
    const int mb = blockIdx.y;
    const int m0 = mb * 64;

    // A staging: thread t covers x[row am, k-octet q] -> one half8 frag slot
    const int am = t >> 2, q = t & 3;
    _Float16* AhW = Ah + (((am >> 4) * 64) + ((am & 15) | (q << 4))) * 8;
    _Float16* AlW = Al + (((am >> 4) * 64) + ((am & 15) | (q << 4))) * 8;
    const float* xP = x + (size_t)(m0 + am) * 2048 + kk * 512 + q * 8;

    floatx4 acc[4][4] = {};

    for (int it = 0; it < 16; ++it) {
        const float4 v0 = *(const float4*)(xP + it * 32);
        const float4 v1 = *(const float4*)(xP + it * 32 + 4);
        const int kc = kk * 16 + it;
        __syncthreads();
        const _Float16* bh_src = Wh + (size_t)kc * 16 * 512;
        const _Float16* bl_src = Wl + (size_t)kc * 16 * 512;
        #pragma unroll
        for (int i = 0; i < 4; ++i) {
            const int c = w * 4 + i;
            gload_lds16(bh_src + (size_t)c * 512 + lane * 8, Bh + c * 512);
            gload_lds16(bl_src + (size_t)c * 512 + lane * 8, Bl + c * 512);
        }
        half8 h8, l8;
        {
            const float vv[8] = {v0.x, v0.y, v0.z, v0.w, v1.x, v1.y, v1.z, v1.w};
            #pragma unroll
            for (int i = 0; i < 8; ++i) {
                const _Float16 hi = (_Float16)vv[i];
                h8[i] = hi;
                l8[i] = (_Float16)(vv[i] - (float)hi);
            }
        }
        *(half8*)AhW = h8;
        *(half8*)AlW = l8;
        __syncthreads();

        half8 ah[4], al[4], bh[4], bl[4];
        #pragma unroll
        for (int s = 0; s < 4; ++s) {
            ah[s] = *(const half8*)(Ah + (s * 64 + lane) * 8);
            al[s] = *(const half8*)(Al + (s * 64 + lane) * 8);
        }
        #pragma unroll
        for (int ni = 0; ni < 4; ++ni) {
            bh[ni] = *(const half8*)(Bh + ((w * 4 + ni) * 64 + lane) * 8);
            bl[ni] = *(const half8*)(Bl + ((w * 4 + ni) * 64 + lane) * 8);
        }
        #pragma unroll
        for (int mi = 0; mi < 4; ++mi) {
            #pragma unroll
            for (int ni = 0; ni < 4; ++ni) {
                acc[mi][ni] = __builtin_amdgcn_mfma_f32_16x16x32_f16(ah[mi], bl[ni], acc[mi][ni], 0, 0, 0);
                acc[mi][ni] = __builtin_amdgcn_mfma_f32_16x16x32_f16(al[mi], bh[ni], acc[mi][ni], 0, 0, 0);
                acc[mi][ni] = __builtin_amdgcn_mfma_f32_16x16x32_f16(ah[mi], bh[ni], acc[mi][ni], 0, 0, 0);
            }
        }
    }

    float* Pk = P + (size_t)kk * 2097152;
    #pragma unroll
    for (int mi = 0; mi < 4; ++mi) {
        #pragma unroll
        for (int ni = 0; ni < 4; ++ni) {
            const int col = w * 64 + ni * 16 + (lane & 15);
            const int rowBase = m0 + mi * 16 + (lane >> 4) * 4;
            #pragma unroll
            for (int r = 0; r < 4; ++r)
                Pk[(size_t)(rowBase + r) * 256 + col] = acc[mi][ni][r];
        }
    }
}

// ============ finalize: reduce split-K, +bias, emit embh/embl/enorm =========
// grid 1024 x 256. Thread: row = blk*8 + t>>5, col-octet q = t&31.
__global__ __launch_bounds__(256) void finalize(
    const float* __restrict__ P, const float* __restrict__ b_enc,
    _Float16* __restrict__ eh, _Float16* __restrict__ el,
    float* __restrict__ enorm)
{
    const int t = threadIdx.x;
    const int row = blockIdx.x * 8 + (t >> 5);
    const int q = t & 31;
    const float* p = P + (size_t)row * 256 + q * 8;

    float4 s0 = *(const float4*)(p);
    float4 s1 = *(const float4*)(p + 4);
    #pragma unroll
    for (int kk = 1; kk < 4; ++kk) {
        const float4 a0 = *(const float4*)(p + (size_t)kk * 2097152);
        const float4 a1 = *(const float4*)(p + (size_t)kk * 2097152 + 4);
        s0.x += a0.x; s0.y += a0.y; s0.z += a0.z; s0.w += a0.w;
        s1.x += a1.x; s1.y += a1.y; s1.z += a1.z; s1.w += a1.w;
    }
    const float4 b0 = *(const float4*)(b_enc + q * 8);
    const float4 b1 = *(const float4*)(b_enc + q * 8 + 4);
    const float inv = 1.0f / 256.0f;
    float v[8];
    v[0] = s0.x * inv + b0.x; v[1] = s0.y * inv + b0.y;
    v[2] = s0.z * inv + b0.z; v[3] = s0.w * inv + b0.w;
    v[4] = s1.x * inv + b1.x; v[5] = s1.y * inv + b1.y;
    v[6] = s1.z * inv + b1.z; v[7] = s1.w * inv + b1.w;

    half8 h, l;
    float ssq = 0.0f;
    #pragma unroll
    for (int i = 0; i < 8; ++i) {
        const _Float16 hi = (_Float16)v[i];
        h[i] = hi;
        l[i] = (_Float16)((v[i] - (float)hi) * 2048.0f);
        ssq += v[i] * v[i];
    }
    const size_t idx = (size_t)(((row >> 4) * 8 + (q >> 2)) * 64
                                + ((row & 15) | ((q & 3) << 4))) * 8;
    *(half8*)(eh + idx) = h;
    *(half8*)(el + idx) = l;

    #pragma unroll
    for (int off = 16; off >= 1; off >>= 1) ssq += __shfl_xor(ssq, off, 64);
    if ((t & 31) == 0) enorm[row] = ssq;
}

// ============ recon = emb @ W_dec + b_dec via fp16 MFMA (r2, validated) =====
__global__ __launch_bounds__(256) void recon_gemm(
    const _Float16* __restrict__ embh, const _Float16* __restrict__ Wdh,
    const float* __restrict__ b_dec, float* __restrict__ out)
{
    __shared__ _Float16 Ah[8 * 64 * 8];   // 8KB
    __shared__ _Float16 Bh[8 * 64 * 8];   // 8KB
    const int t = threadIdx.x, lane = t & 63, w = t >> 6;
    const int wm = w >> 1, wn = w & 1;
    const int nb = blockIdx.x, mb = blockIdx.y;

    floatx4 acc[4][4] = {};

    for (int kc = 0; kc < 8; ++kc) {
        __syncthreads();
        #pragma unroll
        for (int i = 0; i < 2; ++i) {
            const int c = w * 2 + i;
            gload_lds16(embh + (size_t)(((mb * 8 + c) * 8 + kc) * 64 + lane) * 8, Ah + c * 512);
            gload_lds16(Wdh + (size_t)((kc * 128 + nb * 8 + c) * 64 + lane) * 8, Bh + c * 512);
        }
        __syncthreads();
        half8 a[4], b[4];
        #pragma unroll
        for (int mi = 0; mi < 4; ++mi) a[mi] = *(const half8*)(Ah + ((wm * 4 + mi) * 64 + lane) * 8);
        #pragma unroll
        for (int ni = 0; ni < 4; ++ni) b[ni] = *(const half8*)(Bh + ((wn * 4 + ni) * 64 + lane) * 8);
        #pragma unroll
        for (int mi = 0; mi < 4; ++mi)
            #pragma unroll
            for (int ni = 0; ni < 4; ++ni)
                acc[mi][ni] = __builtin_amdgcn_mfma_f32_16x16x32_f16(a[mi], b[ni], acc[mi][ni], 0, 0, 0);
    }

    #pragma unroll
    for (int ni = 0; ni < 4; ++ni) {
        const int col = nb * 128 + (wn * 4 + ni) * 16 + (lane & 15);
        const float bias = b_dec[col];
        #pragma unroll
        for (int mi = 0; mi < 4; ++mi) {
            const int rowBase = mb * 128 + (wm * 4 + mi) * 16 + (lane >> 4) * 4;
            #pragma unroll
            for (int r = 0; r < 4; ++r)
                out[(size_t)(rowBase + r) * 2048 + col] = acc[mi][ni][r] + bias;
        }
    }
}

// ============ row sum-of-squares (creps -> cnorm), ncols=256 ================
__global__ __launch_bounds__(256) void row_sumsq(
    const float* __restrict__ src, float* __restrict__ dst)
{
    const int wid = threadIdx.x >> 6, lane = threadIdx.x & 63;
    const int row = blockIdx.x * 4 + wid;
    const float4 v = *(const float4*)(src + (size_t)row * 256 + lane * 4);
    float s = v.x * v.x + v.y * v.y + v.z * v.z + v.w * v.w;
    #pragma unroll
    for (int off = 32; off >= 1; off >>= 1) s += __shfl_xor(s, off, 64);
    if (lane == 0) dst[row] = s;
}

// ============ dist + softmin via fp16x3 MFMA, no LDS staging ================
// Block: 32 rows x 256 clusters, 4 waves n-split. K=256 in 8 chunks.
__global__ __launch_bounds__(256) void dist_softmin(
    const _Float16* __restrict__ eh, const _Float16* __restrict__ el,
    const _Float16* __restrict__ ch, const _Float16* __restrict__ cl,
    const float* __restrict__ enorm, const float* __restrict__ cnorm,
    float* __restrict__ out)
{
    __shared__ float D[32 * 257];
    __shared__ float MINV[32], SUMV[32];
    const int t = threadIdx.x, lane = t & 63, w = t >> 6;
    const int b0 = blockIdx.x * 32;
    const int mt0 = blockIdx.x * 2;

    floatx4 acc[2][4] = {}, accX[2][4] = {};
    for (int kc = 0; kc < 8; ++kc) {
        half8 ah[2], al[2];
        #pragma unroll
        for (int mi = 0; mi < 2; ++mi) {
            const size_t ab = (size_t)(((mt0 + mi) * 8 + kc) * 64 + lane) * 8;
            ah[mi] = *(const half8*)(eh + ab);
            al[mi] = *(const half8*)(el + ab);
        }
        #pragma unroll
        for (int ni = 0; ni < 4; ++ni) {
            const size_t bb = (size_t)((kc * 16 + (w * 4 + ni)) * 64 + lane) * 8;
            const half8 bh = *(const half8*)(ch + bb);
            const half8 bl = *(const half8*)(cl + bb);
            #pragma unroll
            for (int mi = 0; mi < 2; ++mi) {
                acc[mi][ni]  = __builtin_amdgcn_mfma_f32_16x16x32_f16(ah[mi], bh, acc[mi][ni], 0, 0, 0);
                accX[mi][ni] = __builtin_amdgcn_mfma_f32_16x16x32_f16(ah[mi], bl, accX[mi][ni], 0, 0, 0);
                accX[mi][ni] = __builtin_amdgcn_mfma_f32_16x16x32_f16(al[mi], bh, accX[mi][ni], 0, 0, 0);
            }
        }
    }

    const float invs = 1.0f / 2048.0f;
    #pragma unroll
    for (int mi = 0; mi < 2; ++mi) {
        #pragma unroll
        for (int ni = 0; ni < 4; ++ni) {
            const int k = w * 64 + ni * 16 + (lane & 15);
            const float cn = cnorm[k];
            #pragma unroll
            for (int r = 0; r < 4; ++r) {
                const int rl = mi * 16 + (lane >> 4) * 4 + r;
                const float S = acc[mi][ni][r] + accX[mi][ni][r] * invs;
                D[rl * 257 + k] = enorm[b0 + rl] - 2.0f * S + cn;
            }
        }
    }
    __syncthreads();

    // phase 1: per-row min over 256, then sum of exp
    #pragma unroll
    for (int rr = 0; rr < 8; ++rr) {
        const int r = w * 8 + rr;
        const float d0 = D[r * 257 + lane +   0];
        const float d1 = D[r * 257 + lane +  64];
        const float d2 = D[r * 257 + lane + 128];
        const float d3 = D[r * 257 + lane + 192];
        float mn = fminf(fminf(d0, d1), fminf(d2, d3));
        #pragma unroll
        for (int off = 32; off >= 1; off >>= 1) mn = fminf(mn, __shfl_xor(mn, off, 64));
        float s = expf(-ALPHA_F * (d0 - mn)) + expf(-ALPHA_F * (d1 - mn))
                + expf(-ALPHA_F * (d2 - mn)) + expf(-ALPHA_F * (d3 - mn));
        #pragma unroll
        for (int off = 32; off >= 1; off >>= 1) s += __shfl_xor(s, off, 64);
        if (lane == 0) { MINV[r] = mn; SUMV[r] = s; }
    }
    __syncthreads();

    // phase 2: weighted = d * exp(-a*(d-min)) / sum, out[k][b] coalesced
    const int b = t & 31, kg = t >> 5;
    const float mn = MINV[b], sv = SUMV[b];
    #pragma unroll
    for (int kk = 0; kk < 32; ++kk) {
        const int k = kk * 8 + kg;
        const float dv = D[b * 257 + k];
        out[(size_t)k * 8192 + b0 + b] = dv * expf(-ALPHA_F * (dv - mn)) / sv;
    }
}

// ================= launch ==================================================
extern "C" void kernel_launch(void* const* d_in, const int* in_sizes, int n_in,
                              void* d_out, int out_size, void* d_ws, size_t ws_size,
                              hipStream_t stream) {
    const float* x     = (const float*)d_in[0];   // [8192,2048]
    const float* W_enc = (const float*)d_in[1];   // [2048,256]
    const float* b_enc = (const float*)d_in[2];   // [256]
    const float* W_dec = (const float*)d_in[3];   // [256,2048]
    const float* b_dec = (const float*)d_in[4];   // [2048]
    const float* creps = (const float*)d_in[5];   // [256,256]

    float* out_w   = (float*)d_out;               // [256,8192]
    float* out_rec = out_w + (size_t)256 * 8192;  // [8192,2048]
    float* P       = out_rec;                     // split-K partials (32MB of 64MB)

    float*     enorm = (float*)d_ws;                       // 32 KB
    float*     cnorm = enorm + 8192;                       // 1 KB
    _Float16*  embh  = (_Float16*)(cnorm + 256);           // 4 MB, frag-order
    _Float16*  embl  = embh + (size_t)8192 * 256;          // 4 MB
    _Float16*  Whf   = embl + (size_t)8192 * 256;          // 1 MB
    _Float16*  Wlf   = Whf + (size_t)2048 * 256;           // 1 MB
    _Float16*  Wdh   = Wlf + (size_t)2048 * 256;           // 1 MB
    _Float16*  crh   = Wdh + (size_t)256 * 2048;           // 128 KB
    _Float16*  crl   = crh + (size_t)256 * 256;            // 128 KB

    split_wenc<<<256, 256, 0, stream>>>(W_enc, Whf, Wlf);
    split_wdec<<<256, 256, 0, stream>>>(W_dec, Wdh);
    split_creps<<<32, 256, 0, stream>>>(creps, crh, crl);
    row_sumsq<<<64, 256, 0, stream>>>(creps, cnorm);

    // emb partial sums (split-K=4) into out_rec scratch region
    emb_gemm<<<dim3(4, 128), 256, 0, stream>>>(x, Whf, Wlf, P);

    // reduce + bias -> embh/embl/enorm
    finalize<<<1024, 256, 0, stream>>>(P, b_enc, embh, embl, enorm);

    // weighted_dist (output 0)
    dist_softmin<<<256, 256, 0, stream>>>(embh, embl, crh, crl, enorm, cnorm, out_w);

    // reconstruction (output 1) — overwrites the partials region
    recon_gemm<<<dim3(16, 64), 256, 0, stream>>>(embh, Wdh, b_dec, out_rec);
}